// Round 7
// baseline (92.642 us; speedup 1.0000x reference)
//
#include <hip/hip_runtime.h>
#include <math.h>

constexpr int E = 4;
constexpr int D = 32;
constexpr int K = 16;
constexpr int H = 32;

// f32 -> nearest bf16-representable f32 (RNE, matches jax/ml_dtypes cast)
__device__ __forceinline__ float bf16r(float f) {
    unsigned int u = __float_as_uint(f);
    u = (u + 0x7FFFu + ((u >> 16) & 1u)) & 0xFFFF0000u;
    return __uint_as_float(u);
}
// rounded bf16 bit-pattern (top 16 bits) of f32
__device__ __forceinline__ unsigned int bf16top(float f) {
    unsigned int u = __float_as_uint(f);
    return (u + 0x7FFFu + ((u >> 16) & 1u)) >> 16;
}

// ---- prep: bf16-round all weight arrays into d_ws (flat f32) -------------
// layout: [0,32) rw1 | [32,64) rb1 | [64,192) rw2 | [192,196) rb2 |
//         [196,1220) wf | [1220,1732) wsp | [1732,2244) wrk | [2244,2756) wwv
__global__ void mote_prep(const float* __restrict__ r1, const float* __restrict__ b1,
                          const float* __restrict__ r2, const float* __restrict__ b2,
                          const float* __restrict__ f,  const float* __restrict__ sp,
                          const float* __restrict__ rk, const float* __restrict__ wv,
                          float* __restrict__ ws)
{
    int t = blockIdx.x * blockDim.x + threadIdx.x;
    float v;
    if      (t <   32) v = r1[t];
    else if (t <   64) v = b1[t - 32];
    else if (t <  192) v = r2[t - 64];
    else if (t <  196) v = b2[t - 192];
    else if (t < 1220) v = f [t - 196];
    else if (t < 1732) v = sp[t - 1220];
    else if (t < 2244) v = rk[t - 1732];
    else if (t < 2756) v = wv[t - 2244];
    else return;
    ws[t] = bf16r(v);
}

// LDS row stride in u16: 32 payload + 8 pad = 40 u16 = 80 B.
// Rows stay 16B-aligned for the b128 write phase; total 256*40*2 = 20480 B
// -> 8 blocks/CU (full 160 KiB).
constexpr int LROWU = 40;

// ---- main: round-5 structure (block-wide LDS transpose, 2 barriers per
//      expert) with u16 staging. bf16-cast inputs -> f64 router/softmax/top2,
//      f32 experts, bf16-grid outputs stored as f32 via full-line writes.
__global__ __launch_bounds__(256) void mote_main(
    const float* __restrict__ x_in, int B,
    const float* __restrict__ ws,
    float* __restrict__ out_emb, float* __restrict__ out_rw,
    float* __restrict__ out_mask)
{
    __shared__ unsigned short lds[256 * LROWU];   // 20480 B

    const int tid = threadIdx.x;
    const size_t blockbase = (size_t)blockIdx.x * 256;
    const int b = (int)blockbase + tid;
    const bool valid = b < B;

    const float* rw1 = ws;
    const float* rb1 = ws + 32;
    const float* rw2 = ws + 64;
    const float* rb2 = ws + 192;
    const float* wf  = ws + 196;
    const float* wsp = ws + 1220;
    const float* wrk = ws + 1732;
    const float* wwv = ws + 2244;

    const float  xb = bf16r(valid ? x_in[b] : 0.0f);   // bf16-cast input
    const double xd = (double)xb;

    // ---------------- router MLP in f64 (identical numerics since round 4) --
    double l0 = (double)rb2[0], l1 = (double)rb2[1];
    double l2 = (double)rb2[2], l3 = (double)rb2[3];
#pragma unroll
    for (int j = 0; j < H; ++j) {
        const double h = fmax(fma(xd, (double)rw1[j], (double)rb1[j]), 0.0);
        l0 = fma(h, (double)rw2[j * E + 0], l0);
        l1 = fma(h, (double)rw2[j * E + 1], l1);
        l2 = fma(h, (double)rw2[j * E + 2], l2);
        l3 = fma(h, (double)rw2[j * E + 3], l3);
    }

    // ---------------- softmax in f64 ----------------
    double w[E];
    {
        const double mx = fmax(fmax(l0, l1), fmax(l2, l3));
        w[0] = exp(l0 - mx); w[1] = exp(l1 - mx);
        w[2] = exp(l2 - mx); w[3] = exp(l3 - mx);
        const double s = w[0] + w[1] + w[2] + w[3];
        w[0] /= s; w[1] /= s; w[2] /= s; w[3] /= s;
    }

    // ---------------- top-2, stable (lower index on ties) ----------------
    int i1 = 0;
#pragma unroll
    for (int e = 1; e < E; ++e) if (w[e] > w[i1]) i1 = e;
    int i2 = (i1 == 0) ? 1 : 0;
#pragma unroll
    for (int e = 0; e < E; ++e) if (e != i1 && w[e] > w[i2]) i2 = e;

    float dw[E] = {0.f, 0.f, 0.f, 0.f};
    float mk[E] = {0.f, 0.f, 0.f, 0.f};
    dw[i1] = (float)w[i1]; dw[i2] = (float)w[i2];
    mk[i1] = 1.0f;         mk[i2] = 1.0f;

    // small outputs (f32 on bf16 grid), 16B contiguous per lane = full lines
    if (valid) {
        *reinterpret_cast<float4*>(out_rw + (size_t)E * b) =
            make_float4(bf16r((float)w[0]), bf16r((float)w[1]),
                        bf16r((float)w[2]), bf16r((float)w[3]));
        *reinterpret_cast<float4*>(out_mask + (size_t)E * b) =
            make_float4(mk[0], mk[1], mk[2], mk[3]);
    }

    float acc[D];

    // Per expert: stage this thread's 32 outputs (weighted, bf16-rounded,
    // u16 bit patterns) into LDS, barrier, then block-wide cooperative
    // store: idx = it*256+tid, row = idx>>3, quad = idx&7 -> each row's
    // 128B output chunk covered by 8 lanes = full 64B lines only.
#define STAGE_AND_STORE(EIDX, DWV)                                              \
    do {                                                                        \
        __syncthreads(); /* prior expert's LDS reads complete (WAR) */          \
        _Pragma("unroll")                                                       \
        for (int c = 0; c < 4; ++c) {                                           \
            uint4 pk;                                                           \
            pk.x = bf16top(acc[c*8+0] * (DWV)) | (bf16top(acc[c*8+1] * (DWV)) << 16); \
            pk.y = bf16top(acc[c*8+2] * (DWV)) | (bf16top(acc[c*8+3] * (DWV)) << 16); \
            pk.z = bf16top(acc[c*8+4] * (DWV)) | (bf16top(acc[c*8+5] * (DWV)) << 16); \
            pk.w = bf16top(acc[c*8+6] * (DWV)) | (bf16top(acc[c*8+7] * (DWV)) << 16); \
            *reinterpret_cast<uint4*>(&lds[tid * LROWU + c * 8]) = pk;          \
        }                                                                       \
        __syncthreads(); /* writes visible (RAW) */                             \
        _Pragma("unroll")                                                       \
        for (int it = 0; it < 8; ++it) {                                        \
            const int idx  = it * 256 + tid;                                    \
            const int row  = idx >> 3;                                          \
            const int quad = idx & 7;                                           \
            const uint2 v =                                                     \
                *reinterpret_cast<const uint2*>(&lds[row * LROWU + quad * 4]);  \
            const float4 o = make_float4(                                       \
                __uint_as_float(v.x << 16), __uint_as_float(v.x & 0xFFFF0000u), \
                __uint_as_float(v.y << 16), __uint_as_float(v.y & 0xFFFF0000u));\
            if (blockbase + row < (size_t)B)                                    \
                *reinterpret_cast<float4*>(out_emb + (blockbase + row) * (E * D)\
                                           + (EIDX) * D + quad * 4) = o;        \
        }                                                                       \
    } while (0)

    // expert 0: fourier
    {
        float phi[2 * K];
#pragma unroll
        for (int k = 0; k < K; ++k) {
            float sn, cn;
            sincosf(xb * (float)(k + 1), &sn, &cn);
            phi[k]     = sn;
            phi[K + k] = cn;
        }
#pragma unroll
        for (int d = 0; d < D; ++d) acc[d] = 0.0f;
#pragma unroll
        for (int k = 0; k < 2 * K; ++k) {
            const float p = phi[k];
#pragma unroll
            for (int d = 0; d < D; ++d)
                acc[d] = fmaf(p, wf[k * D + d], acc[d]);
        }
        STAGE_AND_STORE(0, dw[0]);
    }

    // expert 1: spline relu(x-knot)^3
    {
        float phi[K];
#pragma unroll
        for (int k = 0; k < K; ++k) {
            const float knot = (float)(-2.0 + (double)k * (4.0 / 15.0));
            const float r = fmaxf(xb - knot, 0.0f);
            phi[k] = r * r * r;
        }
#pragma unroll
        for (int d = 0; d < D; ++d) acc[d] = 0.0f;
#pragma unroll
        for (int k = 0; k < K; ++k) {
            const float p = phi[k];
#pragma unroll
            for (int d = 0; d < D; ++d)
                acc[d] = fmaf(p, wsp[k * D + d], acc[d]);
        }
        STAGE_AND_STORE(1, dw[1]);
    }

    // expert 2: rkhs gaussian exp(-4 t^2)
    {
        float phi[K];
#pragma unroll
        for (int k = 0; k < K; ++k) {
            const float knot = (float)(-2.0 + (double)k * (4.0 / 15.0));
            const float t = xb - knot;
            phi[k] = expf(-4.0f * t * t);
        }
#pragma unroll
        for (int d = 0; d < D; ++d) acc[d] = 0.0f;
#pragma unroll
        for (int k = 0; k < K; ++k) {
            const float p = phi[k];
#pragma unroll
            for (int d = 0; d < D; ++d)
                acc[d] = fmaf(p, wrk[k * D + d], acc[d]);
        }
        STAGE_AND_STORE(2, dw[2]);
    }

    // expert 3: ricker wavelet (1-z^2) exp(-z^2/2), z = 2 (x - knot)
    {
        float phi[K];
#pragma unroll
        for (int k = 0; k < K; ++k) {
            const float knot = (float)(-2.0 + (double)k * (4.0 / 15.0));
            const float z  = (xb - knot) * 2.0f;
            const float z2 = z * z;
            phi[k] = (1.0f - z2) * expf(-0.5f * z2);
        }
#pragma unroll
        for (int d = 0; d < D; ++d) acc[d] = 0.0f;
#pragma unroll
        for (int k = 0; k < K; ++k) {
            const float p = phi[k];
#pragma unroll
            for (int d = 0; d < D; ++d)
                acc[d] = fmaf(p, wwv[k * D + d], acc[d]);
        }
        STAGE_AND_STORE(3, dw[3]);
    }
#undef STAGE_AND_STORE
}

extern "C" void kernel_launch(void* const* d_in, const int* in_sizes, int n_in,
                              void* d_out, int out_size, void* d_ws, size_t ws_size,
                              hipStream_t stream)
{
    const int B = in_sizes[0];   // timestamp_input (B,1) f32
    const float* x   = (const float*)d_in[0];
    const float* rw1 = (const float*)d_in[1];
    const float* rb1 = (const float*)d_in[2];
    const float* rw2 = (const float*)d_in[3];
    const float* rb2 = (const float*)d_in[4];
    const float* wf  = (const float*)d_in[5];
    const float* wsp = (const float*)d_in[6];
    const float* wrk = (const float*)d_in[7];
    const float* wwv = (const float*)d_in[8];

    float* ws = (float*)d_ws;

    // tuple layout, flat f32 (bf16-grained values) in return order:
    //   final_embedding (B*128) | raw_weights (B*4) | mask (B*4 as 1.0/0.0)
    float* out      = (float*)d_out;
    float* out_emb  = out;
    float* out_rw   = out + (size_t)B * (E * D);
    float* out_mask = out_rw + (size_t)B * E;

    hipLaunchKernelGGL(mote_prep, dim3(11), dim3(256), 0, stream,
                       rw1, rb1, rw2, rb2, wf, wsp, wrk, wwv, ws);

    const int block = 256;
    const int grid  = (B + block - 1) / block;
    hipLaunchKernelGGL(mote_main, dim3(grid), dim3(block), 0, stream,
                       x, B, ws, out_emb, out_rw, out_mask);
}

// Round 8
// 75.439 us; speedup vs baseline: 1.2280x; 1.2280x over previous
//
#include <hip/hip_runtime.h>
#include <math.h>

constexpr int E = 4;
constexpr int D = 32;
constexpr int K = 16;
constexpr int H = 32;

constexpr int BLK = 128;   // threads per block = rows per tile (2 waves)

// f32 -> nearest bf16-representable f32 (RNE, matches jax/ml_dtypes cast)
__device__ __forceinline__ float bf16r(float f) {
    unsigned int u = __float_as_uint(f);
    u = (u + 0x7FFFu + ((u >> 16) & 1u)) & 0xFFFF0000u;
    return __uint_as_float(u);
}

// ---- prep: bf16-round all weight arrays into d_ws (flat f32) -------------
// layout: [0,32) rw1 | [32,64) rb1 | [64,192) rw2 | [192,196) rb2 |
//         [196,1220) wf | [1220,1732) wsp | [1732,2244) wrk | [2244,2756) wwv
__global__ void mote_prep(const float* __restrict__ r1, const float* __restrict__ b1,
                          const float* __restrict__ r2, const float* __restrict__ b2,
                          const float* __restrict__ f,  const float* __restrict__ sp,
                          const float* __restrict__ rk, const float* __restrict__ wv,
                          float* __restrict__ ws)
{
    int t = blockIdx.x * blockDim.x + threadIdx.x;
    float v;
    if      (t <   32) v = r1[t];
    else if (t <   64) v = b1[t - 32];
    else if (t <  192) v = r2[t - 64];
    else if (t <  196) v = b2[t - 192];
    else if (t < 1220) v = f [t - 196];
    else if (t < 1732) v = sp[t - 1220];
    else if (t < 2244) v = rk[t - 1732];
    else if (t < 2756) v = wv[t - 2244];
    else return;
    ws[t] = bf16r(v);
}

// LDS row stride: 32 f32 payload + 4 pad. 16B-aligned rows;
// (row*36 + quad*4) mod 32 = 4*((row+quad)&7) -> even bank spread in both
// the write phase (fixed quad, varying row) and read phase (8 rows x 8 quads).
// Total: 128 * 36 * 4 = 18432 B -> 8 blocks/CU (147/160 KiB).
constexpr int LROW = 36;

// ---- main: round-5 structure (block-wide f32 LDS transpose, 2 barriers per
//      expert) at BLOCK=128: 8 independent barrier groups per CU so store
//      bursts from different groups interleave into a continuous stream.
//      bf16-cast inputs -> f64 router/softmax/top2, f32 experts, bf16-grid
//      outputs stored as f32 via full-line writes. Numerics identical to r5.
__global__ __launch_bounds__(BLK) void mote_main(
    const float* __restrict__ x_in, int B,
    const float* __restrict__ ws,
    float* __restrict__ out_emb, float* __restrict__ out_rw,
    float* __restrict__ out_mask)
{
    __shared__ float lds[BLK * LROW];

    const int tid = threadIdx.x;
    const size_t blockbase = (size_t)blockIdx.x * BLK;
    const int b = (int)blockbase + tid;
    const bool valid = b < B;

    const float* rw1 = ws;
    const float* rb1 = ws + 32;
    const float* rw2 = ws + 64;
    const float* rb2 = ws + 192;
    const float* wf  = ws + 196;
    const float* wsp = ws + 1220;
    const float* wrk = ws + 1732;
    const float* wwv = ws + 2244;

    const float  xb = bf16r(valid ? x_in[b] : 0.0f);   // bf16-cast input
    const double xd = (double)xb;

    // ---------------- router MLP in f64 (identical numerics since round 4) --
    double l0 = (double)rb2[0], l1 = (double)rb2[1];
    double l2 = (double)rb2[2], l3 = (double)rb2[3];
#pragma unroll
    for (int j = 0; j < H; ++j) {
        const double h = fmax(fma(xd, (double)rw1[j], (double)rb1[j]), 0.0);
        l0 = fma(h, (double)rw2[j * E + 0], l0);
        l1 = fma(h, (double)rw2[j * E + 1], l1);
        l2 = fma(h, (double)rw2[j * E + 2], l2);
        l3 = fma(h, (double)rw2[j * E + 3], l3);
    }

    // ---------------- softmax in f64 ----------------
    double w[E];
    {
        const double mx = fmax(fmax(l0, l1), fmax(l2, l3));
        w[0] = exp(l0 - mx); w[1] = exp(l1 - mx);
        w[2] = exp(l2 - mx); w[3] = exp(l3 - mx);
        const double s = w[0] + w[1] + w[2] + w[3];
        w[0] /= s; w[1] /= s; w[2] /= s; w[3] /= s;
    }

    // ---------------- top-2, stable (lower index on ties) ----------------
    int i1 = 0;
#pragma unroll
    for (int e = 1; e < E; ++e) if (w[e] > w[i1]) i1 = e;
    int i2 = (i1 == 0) ? 1 : 0;
#pragma unroll
    for (int e = 0; e < E; ++e) if (e != i1 && w[e] > w[i2]) i2 = e;

    float dw[E] = {0.f, 0.f, 0.f, 0.f};
    float mk[E] = {0.f, 0.f, 0.f, 0.f};
    dw[i1] = (float)w[i1]; dw[i2] = (float)w[i2];
    mk[i1] = 1.0f;         mk[i2] = 1.0f;

    // small outputs (f32 on bf16 grid), 16B contiguous per lane = full lines
    if (valid) {
        *reinterpret_cast<float4*>(out_rw + (size_t)E * b) =
            make_float4(bf16r((float)w[0]), bf16r((float)w[1]),
                        bf16r((float)w[2]), bf16r((float)w[3]));
        *reinterpret_cast<float4*>(out_mask + (size_t)E * b) =
            make_float4(mk[0], mk[1], mk[2], mk[3]);
    }

    float acc[D];

    // Per expert: stage this thread's 32 outputs (weighted, bf16-rounded f32)
    // into LDS, barrier, then block-wide cooperative store:
    // idx = it*BLK+tid, row = idx>>3, quad = idx&7 -> each row's 128B chunk
    // covered by 8 consecutive lanes = full 64B lines only.
#define STAGE_AND_STORE(EIDX, DWV)                                              \
    do {                                                                        \
        __syncthreads(); /* prior expert's LDS reads complete (WAR) */          \
        _Pragma("unroll")                                                       \
        for (int q = 0; q < D / 4; ++q)                                         \
            *reinterpret_cast<float4*>(&lds[tid * LROW + q * 4]) =              \
                make_float4(bf16r(acc[4*q+0] * (DWV)), bf16r(acc[4*q+1] * (DWV)), \
                            bf16r(acc[4*q+2] * (DWV)), bf16r(acc[4*q+3] * (DWV))); \
        __syncthreads(); /* writes visible (RAW) */                             \
        _Pragma("unroll")                                                       \
        for (int it = 0; it < 8; ++it) {                                        \
            const int idx  = it * BLK + tid;                                    \
            const int row  = idx >> 3;                                          \
            const int quad = idx & 7;                                           \
            if (blockbase + row < (size_t)B)                                    \
                *reinterpret_cast<float4*>(out_emb + (blockbase + row) * (E * D)\
                                           + (EIDX) * D + quad * 4) =           \
                    *reinterpret_cast<const float4*>(&lds[row * LROW + quad * 4]); \
        }                                                                       \
    } while (0)

    // expert 0: fourier
    {
        float phi[2 * K];
#pragma unroll
        for (int k = 0; k < K; ++k) {
            float sn, cn;
            sincosf(xb * (float)(k + 1), &sn, &cn);
            phi[k]     = sn;
            phi[K + k] = cn;
        }
#pragma unroll
        for (int d = 0; d < D; ++d) acc[d] = 0.0f;
#pragma unroll
        for (int k = 0; k < 2 * K; ++k) {
            const float p = phi[k];
#pragma unroll
            for (int d = 0; d < D; ++d)
                acc[d] = fmaf(p, wf[k * D + d], acc[d]);
        }
        STAGE_AND_STORE(0, dw[0]);
    }

    // expert 1: spline relu(x-knot)^3
    {
        float phi[K];
#pragma unroll
        for (int k = 0; k < K; ++k) {
            const float knot = (float)(-2.0 + (double)k * (4.0 / 15.0));
            const float r = fmaxf(xb - knot, 0.0f);
            phi[k] = r * r * r;
        }
#pragma unroll
        for (int d = 0; d < D; ++d) acc[d] = 0.0f;
#pragma unroll
        for (int k = 0; k < K; ++k) {
            const float p = phi[k];
#pragma unroll
            for (int d = 0; d < D; ++d)
                acc[d] = fmaf(p, wsp[k * D + d], acc[d]);
        }
        STAGE_AND_STORE(1, dw[1]);
    }

    // expert 2: rkhs gaussian exp(-4 t^2)
    {
        float phi[K];
#pragma unroll
        for (int k = 0; k < K; ++k) {
            const float knot = (float)(-2.0 + (double)k * (4.0 / 15.0));
            const float t = xb - knot;
            phi[k] = expf(-4.0f * t * t);
        }
#pragma unroll
        for (int d = 0; d < D; ++d) acc[d] = 0.0f;
#pragma unroll
        for (int k = 0; k < K; ++k) {
            const float p = phi[k];
#pragma unroll
            for (int d = 0; d < D; ++d)
                acc[d] = fmaf(p, wrk[k * D + d], acc[d]);
        }
        STAGE_AND_STORE(2, dw[2]);
    }

    // expert 3: ricker wavelet (1-z^2) exp(-z^2/2), z = 2 (x - knot)
    {
        float phi[K];
#pragma unroll
        for (int k = 0; k < K; ++k) {
            const float knot = (float)(-2.0 + (double)k * (4.0 / 15.0));
            const float z  = (xb - knot) * 2.0f;
            const float z2 = z * z;
            phi[k] = (1.0f - z2) * expf(-0.5f * z2);
        }
#pragma unroll
        for (int d = 0; d < D; ++d) acc[d] = 0.0f;
#pragma unroll
        for (int k = 0; k < K; ++k) {
            const float p = phi[k];
#pragma unroll
            for (int d = 0; d < D; ++d)
                acc[d] = fmaf(p, wwv[k * D + d], acc[d]);
        }
        STAGE_AND_STORE(3, dw[3]);
    }
#undef STAGE_AND_STORE
}

extern "C" void kernel_launch(void* const* d_in, const int* in_sizes, int n_in,
                              void* d_out, int out_size, void* d_ws, size_t ws_size,
                              hipStream_t stream)
{
    const int B = in_sizes[0];   // timestamp_input (B,1) f32
    const float* x   = (const float*)d_in[0];
    const float* rw1 = (const float*)d_in[1];
    const float* rb1 = (const float*)d_in[2];
    const float* rw2 = (const float*)d_in[3];
    const float* rb2 = (const float*)d_in[4];
    const float* wf  = (const float*)d_in[5];
    const float* wsp = (const float*)d_in[6];
    const float* wrk = (const float*)d_in[7];
    const float* wwv = (const float*)d_in[8];

    float* ws = (float*)d_ws;

    // tuple layout, flat f32 (bf16-grained values) in return order:
    //   final_embedding (B*128) | raw_weights (B*4) | mask (B*4 as 1.0/0.0)
    float* out      = (float*)d_out;
    float* out_emb  = out;
    float* out_rw   = out + (size_t)B * (E * D);
    float* out_mask = out_rw + (size_t)B * E;

    hipLaunchKernelGGL(mote_prep, dim3(11), dim3(256), 0, stream,
                       rw1, rb1, rw2, rb2, wf, wsp, wrk, wwv, ws);

    const int grid = (B + BLK - 1) / BLK;
    hipLaunchKernelGGL(mote_main, dim3(grid), dim3(BLK), 0, stream,
                       x, B, ws, out_emb, out_rw, out_mask);
}

// Round 9
// 73.051 us; speedup vs baseline: 1.2682x; 1.0327x over previous
//
#include <hip/hip_runtime.h>
#include <math.h>

constexpr int E = 4;
constexpr int D = 32;
constexpr int K = 16;
constexpr int H = 32;

// f32 -> nearest bf16-representable f32 (RNE, matches jax/ml_dtypes cast)
__device__ __forceinline__ float bf16r(float f) {
    unsigned int u = __float_as_uint(f);
    u = (u + 0x7FFFu + ((u >> 16) & 1u)) & 0xFFFF0000u;
    return __uint_as_float(u);
}

// ---- prep: bf16-round all weight arrays into d_ws (flat f32) -------------
// layout: [0,32) rw1 | [32,64) rb1 | [64,192) rw2 | [192,196) rb2 |
//         [196,1220) wf | [1220,1732) wsp | [1732,2244) wrk | [2244,2756) wwv
__global__ void mote_prep(const float* __restrict__ r1, const float* __restrict__ b1,
                          const float* __restrict__ r2, const float* __restrict__ b2,
                          const float* __restrict__ f,  const float* __restrict__ sp,
                          const float* __restrict__ rk, const float* __restrict__ wv,
                          float* __restrict__ ws)
{
    int t = blockIdx.x * blockDim.x + threadIdx.x;
    float v;
    if      (t <   32) v = r1[t];
    else if (t <   64) v = b1[t - 32];
    else if (t <  192) v = r2[t - 64];
    else if (t <  196) v = b2[t - 192];
    else if (t < 1220) v = f [t - 196];
    else if (t < 1732) v = sp[t - 1220];
    else if (t < 2244) v = rk[t - 1732];
    else if (t < 2756) v = wv[t - 2244];
    else return;
    ws[t] = bf16r(v);
}

// LDS row stride: 32 f32 payload + 4 pad -> rows 16B-aligned, and
// (row*36 + quad*4) mod 32 = 4*((row+quad)&7): even bank spread in both the
// write phase (fixed quad, varying row) and read phase (8 rows x 8 quads).
// Per-wave slab: 64 rows. Total 4*64*36*4 = 36864 B.
constexpr int LROW = 36;

// ---- main: wave-private f32 LDS transpose, ZERO barriers.
//      Each wave stages its own 64 rows and stores them; LDS WAR within a
//      wave is ordered by the in-order DS pipe (lgkmcnt), and global stores
//      are never waited on (no vmcnt(0) drain) -> stores from expert e
//      drain in the background under expert e+1's VALU work.
//      bf16-cast inputs -> f64 router/softmax/top2, f32 experts, bf16-grid
//      outputs stored as f32 via full-line writes. Numerics identical to r5.
__global__ __launch_bounds__(256) void mote_main(
    const float* __restrict__ x_in, int B,
    const float* __restrict__ ws,
    float* __restrict__ out_emb, float* __restrict__ out_rw,
    float* __restrict__ out_mask)
{
    __shared__ float sl[4][64][LROW];   // per-wave private slabs

    const int tid  = threadIdx.x;
    const int wid  = tid >> 6;
    const int lane = tid & 63;
    const size_t blockbase = (size_t)blockIdx.x * 256;
    const int b = (int)blockbase + tid;
    const bool valid = b < B;

    const float* rw1 = ws;
    const float* rb1 = ws + 32;
    const float* rw2 = ws + 64;
    const float* rb2 = ws + 192;
    const float* wf  = ws + 196;
    const float* wsp = ws + 1220;
    const float* wrk = ws + 1732;
    const float* wwv = ws + 2244;

    const float  xb = bf16r(valid ? x_in[b] : 0.0f);   // bf16-cast input
    const double xd = (double)xb;

    // ---------------- router MLP in f64 (identical numerics since round 4) --
    double l0 = (double)rb2[0], l1 = (double)rb2[1];
    double l2 = (double)rb2[2], l3 = (double)rb2[3];
#pragma unroll
    for (int j = 0; j < H; ++j) {
        const double h = fmax(fma(xd, (double)rw1[j], (double)rb1[j]), 0.0);
        l0 = fma(h, (double)rw2[j * E + 0], l0);
        l1 = fma(h, (double)rw2[j * E + 1], l1);
        l2 = fma(h, (double)rw2[j * E + 2], l2);
        l3 = fma(h, (double)rw2[j * E + 3], l3);
    }

    // ---------------- softmax in f64 ----------------
    double w[E];
    {
        const double mx = fmax(fmax(l0, l1), fmax(l2, l3));
        w[0] = exp(l0 - mx); w[1] = exp(l1 - mx);
        w[2] = exp(l2 - mx); w[3] = exp(l3 - mx);
        const double s = w[0] + w[1] + w[2] + w[3];
        w[0] /= s; w[1] /= s; w[2] /= s; w[3] /= s;
    }

    // ---------------- top-2, stable (lower index on ties) ----------------
    int i1 = 0;
#pragma unroll
    for (int e = 1; e < E; ++e) if (w[e] > w[i1]) i1 = e;
    int i2 = (i1 == 0) ? 1 : 0;
#pragma unroll
    for (int e = 0; e < E; ++e) if (e != i1 && w[e] > w[i2]) i2 = e;

    float dw[E] = {0.f, 0.f, 0.f, 0.f};
    float mk[E] = {0.f, 0.f, 0.f, 0.f};
    dw[i1] = (float)w[i1]; dw[i2] = (float)w[i2];
    mk[i1] = 1.0f;         mk[i2] = 1.0f;

    // small outputs (f32 on bf16 grid), 16B contiguous per lane = full lines
    if (valid) {
        *reinterpret_cast<float4*>(out_rw + (size_t)E * b) =
            make_float4(bf16r((float)w[0]), bf16r((float)w[1]),
                        bf16r((float)w[2]), bf16r((float)w[3]));
        *reinterpret_cast<float4*>(out_mask + (size_t)E * b) =
            make_float4(mk[0], mk[1], mk[2], mk[3]);
    }

    float acc[D];

    float (*slab)[LROW] = sl[wid];
    const size_t wrowbase = blockbase + (size_t)wid * 64;  // wave's first row
    const int r8 = lane >> 3;       // row sub-index for the store phase
    const int q  = lane & 7;        // quad (16B chunk) index

    // Stage this lane's 32 outputs (weighted, bf16-rounded f32) into the
    // wave's own slab, then the wave cooperatively stores 64 rows:
    // 8 iterations x (8 rows x 128B contiguous) -> full 64B lines only.
    // No __syncthreads anywhere: producer == consumer wave (lockstep);
    // no vmcnt(0) drains -> global stores complete in the background.
#define STAGE_STORE(EIDX, DWV)                                                  \
    do {                                                                        \
        _Pragma("unroll")                                                       \
        for (int c = 0; c < D / 4; ++c)                                         \
            *reinterpret_cast<float4*>(&slab[lane][c * 4]) =                    \
                make_float4(bf16r(acc[4*c+0] * (DWV)), bf16r(acc[4*c+1] * (DWV)), \
                            bf16r(acc[4*c+2] * (DWV)), bf16r(acc[4*c+3] * (DWV))); \
        _Pragma("unroll")                                                       \
        for (int it = 0; it < 8; ++it) {                                        \
            const int row = it * 8 + r8;                                        \
            const float4 v =                                                    \
                *reinterpret_cast<const float4*>(&slab[row][q * 4]);            \
            if (wrowbase + row < (size_t)B)                                     \
                *reinterpret_cast<float4*>(out_emb + (wrowbase + row) * (E * D) \
                                           + (EIDX) * D + q * 4) = v;           \
        }                                                                       \
    } while (0)

    // expert 0: fourier
    {
        float phi[2 * K];
#pragma unroll
        for (int k = 0; k < K; ++k) {
            float sn, cn;
            sincosf(xb * (float)(k + 1), &sn, &cn);
            phi[k]     = sn;
            phi[K + k] = cn;
        }
#pragma unroll
        for (int d = 0; d < D; ++d) acc[d] = 0.0f;
#pragma unroll
        for (int k = 0; k < 2 * K; ++k) {
            const float p = phi[k];
#pragma unroll
            for (int d = 0; d < D; ++d)
                acc[d] = fmaf(p, wf[k * D + d], acc[d]);
        }
        STAGE_STORE(0, dw[0]);
    }

    // expert 1: spline relu(x-knot)^3
    {
        float phi[K];
#pragma unroll
        for (int k = 0; k < K; ++k) {
            const float knot = (float)(-2.0 + (double)k * (4.0 / 15.0));
            const float r = fmaxf(xb - knot, 0.0f);
            phi[k] = r * r * r;
        }
#pragma unroll
        for (int d = 0; d < D; ++d) acc[d] = 0.0f;
#pragma unroll
        for (int k = 0; k < K; ++k) {
            const float p = phi[k];
#pragma unroll
            for (int d = 0; d < D; ++d)
                acc[d] = fmaf(p, wsp[k * D + d], acc[d]);
        }
        STAGE_STORE(1, dw[1]);
    }

    // expert 2: rkhs gaussian exp(-4 t^2)
    {
        float phi[K];
#pragma unroll
        for (int k = 0; k < K; ++k) {
            const float knot = (float)(-2.0 + (double)k * (4.0 / 15.0));
            const float t = xb - knot;
            phi[k] = expf(-4.0f * t * t);
        }
#pragma unroll
        for (int d = 0; d < D; ++d) acc[d] = 0.0f;
#pragma unroll
        for (int k = 0; k < K; ++k) {
            const float p = phi[k];
#pragma unroll
            for (int d = 0; d < D; ++d)
                acc[d] = fmaf(p, wrk[k * D + d], acc[d]);
        }
        STAGE_STORE(2, dw[2]);
    }

    // expert 3: ricker wavelet (1-z^2) exp(-z^2/2), z = 2 (x - knot)
    {
        float phi[K];
#pragma unroll
        for (int k = 0; k < K; ++k) {
            const float knot = (float)(-2.0 + (double)k * (4.0 / 15.0));
            const float z  = (xb - knot) * 2.0f;
            const float z2 = z * z;
            phi[k] = (1.0f - z2) * expf(-0.5f * z2);
        }
#pragma unroll
        for (int d = 0; d < D; ++d) acc[d] = 0.0f;
#pragma unroll
        for (int k = 0; k < K; ++k) {
            const float p = phi[k];
#pragma unroll
            for (int d = 0; d < D; ++d)
                acc[d] = fmaf(p, wwv[k * D + d], acc[d]);
        }
        STAGE_STORE(3, dw[3]);
    }
#undef STAGE_STORE
}

extern "C" void kernel_launch(void* const* d_in, const int* in_sizes, int n_in,
                              void* d_out, int out_size, void* d_ws, size_t ws_size,
                              hipStream_t stream)
{
    const int B = in_sizes[0];   // timestamp_input (B,1) f32
    const float* x   = (const float*)d_in[0];
    const float* rw1 = (const float*)d_in[1];
    const float* rb1 = (const float*)d_in[2];
    const float* rw2 = (const float*)d_in[3];
    const float* rb2 = (const float*)d_in[4];
    const float* wf  = (const float*)d_in[5];
    const float* wsp = (const float*)d_in[6];
    const float* wrk = (const float*)d_in[7];
    const float* wwv = (const float*)d_in[8];

    float* ws = (float*)d_ws;

    // tuple layout, flat f32 (bf16-grained values) in return order:
    //   final_embedding (B*128) | raw_weights (B*4) | mask (B*4 as 1.0/0.0)
    float* out      = (float*)d_out;
    float* out_emb  = out;
    float* out_rw   = out + (size_t)B * (E * D);
    float* out_mask = out_rw + (size_t)B * E;

    hipLaunchKernelGGL(mote_prep, dim3(11), dim3(256), 0, stream,
                       rw1, rb1, rw2, rb2, wf, wsp, wrk, wwv, ws);

    const int block = 256;
    const int grid  = (B + block - 1) / block;
    hipLaunchKernelGGL(mote_main, dim3(grid), dim3(block), 0, stream,
                       x, B, ws, out_emb, out_rw, out_mask);
}